// Round 10
// baseline (92.979 us; speedup 1.0000x reference)
//
#include <hip/hip_runtime.h>
#include <hip/hip_bf16.h>
#include <stdint.h>

#define M_DIM 2048
#define N_DIM 4096
#define K_DIM 4096

#define BM 128
#define BN 128
#define BK 64

typedef __bf16 bf16x8 __attribute__((ext_vector_type(8)));
typedef float f32x4 __attribute__((ext_vector_type(4)));
typedef unsigned short ushort8_t __attribute__((ext_vector_type(8)));

__device__ __forceinline__ unsigned short f32_to_bf16_rne(float f) {
    union { float f; uint32_t u; } cvt;
    cvt.f = f;
    uint32_t u = cvt.u;
    uint32_t r = (u + 0x7fffu + ((u >> 16) & 1u)) >> 16;
    return (unsigned short)r;
}

__device__ __forceinline__ void gload_lds16(const void* g, void* l) {
    __builtin_amdgcn_global_load_lds(
        (__attribute__((address_space(1))) const void*)g,
        (__attribute__((address_space(3))) void*)l,
        16, 0, 0);
}

// ---------------------------------------------------------------------------
__global__ void convert_x_kernel(const float* __restrict__ x,
                                 unsigned short* __restrict__ xb, int n8) {
    int i = blockIdx.x * blockDim.x + threadIdx.x;
    int stride = gridDim.x * blockDim.x;
    for (; i < n8; i += stride) {
        const float4* p = (const float4*)(x + (size_t)i * 8);
        float4 v0 = p[0];
        float4 v1 = p[1];
        ushort8_t o;
        o[0] = f32_to_bf16_rne(v0.x);
        o[1] = f32_to_bf16_rne(v0.y);
        o[2] = f32_to_bf16_rne(v0.z);
        o[3] = f32_to_bf16_rne(v0.w);
        o[4] = f32_to_bf16_rne(v1.x);
        o[5] = f32_to_bf16_rne(v1.y);
        o[6] = f32_to_bf16_rne(v1.z);
        o[7] = f32_to_bf16_rne(v1.w);
        *(ushort8_t*)(xb + (size_t)i * 8) = o;
    }
}

// ---------------------------------------------------------------------------
__global__ void transpose_convert_w(const float* __restrict__ W,
                                    unsigned short* __restrict__ Wt) {
    __shared__ float tile[64][65];
    const int k0 = blockIdx.y * 64;
    const int n0 = blockIdx.x * 64;
    const int t  = threadIdx.x;
    const int tx = t & 15;
    const int ty = t >> 4;

#pragma unroll
    for (int r = 0; r < 4; ++r) {
        int row = ty + 16 * r;
        float4 v = *(const float4*)(W + (size_t)(k0 + row) * N_DIM + n0 + tx * 4);
        tile[row][tx * 4 + 0] = v.x;
        tile[row][tx * 4 + 1] = v.y;
        tile[row][tx * 4 + 2] = v.z;
        tile[row][tx * 4 + 3] = v.w;
    }
    __syncthreads();
#pragma unroll
    for (int r = 0; r < 4; ++r) {
        int nrow = ty + 16 * r;
        ushort4 o;
        o.x = f32_to_bf16_rne(tile[tx * 4 + 0][nrow]);
        o.y = f32_to_bf16_rne(tile[tx * 4 + 1][nrow]);
        o.z = f32_to_bf16_rne(tile[tx * 4 + 2][nrow]);
        o.w = f32_to_bf16_rne(tile[tx * 4 + 3][nrow]);
        *(ushort4*)(Wt + (size_t)(n0 + nrow) * K_DIM + k0 + tx * 4) = o;
    }
}

// ---------------------------------------------------------------------------
// GEMM: C[m][n] = sum_k A[m][k] * Bt[n][k] + bias[n]
// R9's kk-split wave structure at HALF the block (2 WGs/CU for cross-WG
// pipe overlap): BM=BN=128, 256 thr, 4 waves = 2 regions (64x128) x 2
// kk-roles. Per wave: 4 A + 8 B ds_read_b128 -> 32 MFMA (2.67 MFMA/KB,
// proven 0-conflict 128B-row swizzle). Double-buffered 64 KiB LDS ->
// 2 WGs/CU; their barrier rhythms drift, so one WG's LDS burst overlaps
// the other's MFMA burst.
// Ledger: stage tile tau+1 at tile-top (8 gloads/thread); end-of-tile
// lgkmcnt(0) [WAR: cur buf reads done] + vmcnt(0) [RAW: next tile landed;
// issued ~1200cyc earlier so drain is cheap; other WG hides the rest]
// + barrier. Epilogue combines kk pairs through the dead LDS buffers.
// ---------------------------------------------------------------------------
__global__ __launch_bounds__(256, 2) void gemm_bf16(
    const unsigned short* __restrict__ A,
    const unsigned short* __restrict__ Bt,
    const float* __restrict__ bias,
    float* __restrict__ C) {
    __shared__ __align__(16) char smem[65536];
    // A bufs: smem + buf*16384          (2 x 16 KiB)
    // B bufs: smem + 32768 + buf*16384  (2 x 16 KiB)
    // epilogue partials: smem + region*32768 (2 x 32 KiB)

    const int t    = threadIdx.x;
    const int lane = t & 63;
    const int wave = t >> 6;   // 0..3
    const int rm   = wave >> 1;  // 0..1 : 64-row region
    const int kkr  = wave & 1;   // 0/1  : K-half role
    const int lrow = lane & 15;
    const int lhi  = lane >> 4;

    // T1: XCD-aware swizzle (512 WGs, %8==0 -> bijective); each XCD gets
    // 64 consecutive tiles = 2 m-rows x 32 n-cols (A-panel L2 reuse x32).
    const int wg  = blockIdx.x;
    const int swz = (wg & 7) * 64 + (wg >> 3);
    const int m0  = (swz >> 5) * BM;   // 16 m-tiles
    const int n0  = (swz & 31) * BN;   // 32 n-tiles

    // staging: linear LDS dest + inverse-swizzled global source
    auto stage = [&](int nb, int tile) {
        const size_t kb = (size_t)tile * BK;
#pragma unroll
        for (int i = 0; i < 4; ++i) {
            int c   = t + 256 * i;       // 0..1023
            int row = c >> 3, p = c & 7;
            int l   = p ^ (row & 7);
            gload_lds16(A + (size_t)(m0 + row) * K_DIM + kb + l * 8,
                        smem + nb * 16384 + c * 16);
            gload_lds16(Bt + (size_t)(n0 + row) * K_DIM + kb + l * 8,
                        smem + 32768 + nb * 16384 + c * 16);
        }
    };

    f32x4 acc[4][8];  // [mi][nj]: this wave's kk-half of its 64x128 region
#pragma unroll
    for (int i = 0; i < 4; ++i)
#pragma unroll
        for (int j = 0; j < 8; ++j) acc[i][j] = (f32x4)0.0f;

    const int NT = K_DIM / BK;  // 64

    // fragment offsets (row&7 == lrow&7; proven 0-conflict pattern)
    const int rowOffA = (rm * 64 + lrow) * 128;          // + mi*2048, mi 0..3
    const int rowOffB = lrow * 128;                      // + nj*2048, nj 0..7
    const int sK = ((kkr * 4 + lhi) ^ (lrow & 7)) * 16;  // this wave's kk slot

    // prologue: tile 0 -> buf0, publish
    stage(0, 0);
    asm volatile("s_waitcnt vmcnt(0)" ::: "memory");
    __builtin_amdgcn_s_barrier();
    __builtin_amdgcn_sched_barrier(0);

#pragma unroll 2
    for (int tau = 0; tau < NT; ++tau) {
        const int buf   = tau & 1;
        const int nb    = buf ^ 1;
        const int tile2 = (tau + 1 < NT) ? tau + 1 : NT - 1;

        const char* bA = smem + buf * 16384;
        const char* bB = smem + 32768 + buf * 16384;

        // stage next tile first (oldest possible issue -> cheap drain later)
        stage(nb, tile2);

        // ---- P0: nj 0..3 ----
        bf16x8 af[4], bf[4];
#pragma unroll
        for (int mi = 0; mi < 4; ++mi)
            af[mi] = *(const bf16x8*)(bA + rowOffA + mi * 2048 + sK);
#pragma unroll
        for (int nj = 0; nj < 4; ++nj)
            bf[nj] = *(const bf16x8*)(bB + rowOffB + nj * 2048 + sK);
        __builtin_amdgcn_s_setprio(1);
#pragma unroll
        for (int mi = 0; mi < 4; ++mi)
#pragma unroll
            for (int nj = 0; nj < 4; ++nj)
                acc[mi][nj] = __builtin_amdgcn_mfma_f32_16x16x32_bf16(
                    af[mi], bf[nj], acc[mi][nj], 0, 0, 0);
        __builtin_amdgcn_s_setprio(0);

        // ---- P1: nj 4..7 ----
        bf16x8 bg[4];
#pragma unroll
        for (int nj = 0; nj < 4; ++nj)
            bg[nj] = *(const bf16x8*)(bB + rowOffB + (nj + 4) * 2048 + sK);
        __builtin_amdgcn_s_setprio(1);
#pragma unroll
        for (int mi = 0; mi < 4; ++mi)
#pragma unroll
            for (int nj = 0; nj < 4; ++nj)
                acc[mi][nj + 4] = __builtin_amdgcn_mfma_f32_16x16x32_bf16(
                    af[mi], bg[nj], acc[mi][nj + 4], 0, 0, 0);
        __builtin_amdgcn_s_setprio(0);

        // end of tile: WAR (cur-buf reads done) + RAW (next tile landed)
        asm volatile("s_waitcnt vmcnt(0) lgkmcnt(0)" ::: "memory");
        __builtin_amdgcn_s_barrier();
        __builtin_amdgcn_sched_barrier(0);
    }

    // ---- epilogue: combine kk pair via (dead) LDS, write C + bias ----
    if (kkr == 1) {
#pragma unroll
        for (int mi = 0; mi < 4; ++mi)
#pragma unroll
            for (int nj = 0; nj < 8; ++nj)
                *(f32x4*)(smem + rm * 32768 +
                          ((mi * 8 + nj) * 64 + lane) * 16) = acc[mi][nj];
    }
    __syncthreads();
    if (kkr == 0) {
        // C/D layout: col=lane&15, row=(lane>>4)*4+reg
#pragma unroll
        for (int nj = 0; nj < 8; ++nj) {
            int col  = n0 + nj * 16 + lrow;
            float bv = bias[col];
#pragma unroll
            for (int mi = 0; mi < 4; ++mi) {
                f32x4 p = *(const f32x4*)(smem + rm * 32768 +
                                          ((mi * 8 + nj) * 64 + lane) * 16);
                int rbase = m0 + rm * 64 + mi * 16 + lhi * 4;
#pragma unroll
                for (int r = 0; r < 4; ++r) {
                    C[(size_t)(rbase + r) * N_DIM + col] =
                        acc[mi][nj][r] + p[r] + bv;
                }
            }
        }
    }
}

// ---------------------------------------------------------------------------
extern "C" void kernel_launch(void* const* d_in, const int* in_sizes, int n_in,
                              void* d_out, int out_size, void* d_ws, size_t ws_size,
                              hipStream_t stream) {
    const float* x    = (const float*)d_in[0];
    const float* w    = (const float*)d_in[1];
    const float* bias = (const float*)d_in[2];
    float* out        = (float*)d_out;

    unsigned short* xb = (unsigned short*)d_ws;
    unsigned short* wt = (unsigned short*)((char*)d_ws +
                          (size_t)M_DIM * K_DIM * sizeof(unsigned short));

    convert_x_kernel<<<2048, 256, 0, stream>>>(x, xb, M_DIM * K_DIM / 8);

    dim3 tgrid(N_DIM / 64, K_DIM / 64);
    transpose_convert_w<<<tgrid, 256, 0, stream>>>(w, wt);

    dim3 ggrid((M_DIM / BM) * (N_DIM / BN));
    gemm_bf16<<<ggrid, 256, 0, stream>>>(xb, wt, bias, out);
}

// Round 11
// 92.105 us; speedup vs baseline: 1.0095x; 1.0095x over previous
//
#include <hip/hip_runtime.h>
#include <hip/hip_bf16.h>
#include <stdint.h>

#define M_DIM 2048
#define N_DIM 4096
#define K_DIM 4096

#define BM 128
#define BN 256
#define BK 64

typedef __bf16 bf16x8 __attribute__((ext_vector_type(8)));
typedef float f32x4 __attribute__((ext_vector_type(4)));
typedef unsigned short ushort8_t __attribute__((ext_vector_type(8)));

__device__ __forceinline__ unsigned short f32_to_bf16_rne(float f) {
    union { float f; uint32_t u; } cvt;
    cvt.f = f;
    uint32_t u = cvt.u;
    uint32_t r = (u + 0x7fffu + ((u >> 16) & 1u)) >> 16;
    return (unsigned short)r;
}

__device__ __forceinline__ void gload_lds16(const void* g, void* l) {
    __builtin_amdgcn_global_load_lds(
        (__attribute__((address_space(1))) const void*)g,
        (__attribute__((address_space(3))) void*)l,
        16, 0, 0);
}

// ---------------------------------------------------------------------------
__global__ void convert_x_kernel(const float* __restrict__ x,
                                 unsigned short* __restrict__ xb, int n8) {
    int i = blockIdx.x * blockDim.x + threadIdx.x;
    int stride = gridDim.x * blockDim.x;
    for (; i < n8; i += stride) {
        const float4* p = (const float4*)(x + (size_t)i * 8);
        float4 v0 = p[0];
        float4 v1 = p[1];
        ushort8_t o;
        o[0] = f32_to_bf16_rne(v0.x);
        o[1] = f32_to_bf16_rne(v0.y);
        o[2] = f32_to_bf16_rne(v0.z);
        o[3] = f32_to_bf16_rne(v0.w);
        o[4] = f32_to_bf16_rne(v1.x);
        o[5] = f32_to_bf16_rne(v1.y);
        o[6] = f32_to_bf16_rne(v1.z);
        o[7] = f32_to_bf16_rne(v1.w);
        *(ushort8_t*)(xb + (size_t)i * 8) = o;
    }
}

// ---------------------------------------------------------------------------
__global__ void transpose_convert_w(const float* __restrict__ W,
                                    unsigned short* __restrict__ Wt) {
    __shared__ float tile[64][65];
    const int k0 = blockIdx.y * 64;
    const int n0 = blockIdx.x * 64;
    const int t  = threadIdx.x;
    const int tx = t & 15;
    const int ty = t >> 4;

#pragma unroll
    for (int r = 0; r < 4; ++r) {
        int row = ty + 16 * r;
        float4 v = *(const float4*)(W + (size_t)(k0 + row) * N_DIM + n0 + tx * 4);
        tile[row][tx * 4 + 0] = v.x;
        tile[row][tx * 4 + 1] = v.y;
        tile[row][tx * 4 + 2] = v.z;
        tile[row][tx * 4 + 3] = v.w;
    }
    __syncthreads();
#pragma unroll
    for (int r = 0; r < 4; ++r) {
        int nrow = ty + 16 * r;
        ushort4 o;
        o.x = f32_to_bf16_rne(tile[tx * 4 + 0][nrow]);
        o.y = f32_to_bf16_rne(tile[tx * 4 + 1][nrow]);
        o.z = f32_to_bf16_rne(tile[tx * 4 + 2][nrow]);
        o.w = f32_to_bf16_rne(tile[tx * 4 + 3][nrow]);
        *(ushort4*)(Wt + (size_t)(n0 + nrow) * K_DIM + k0 + tx * 4) = o;
    }
}

// ---------------------------------------------------------------------------
// GEMM: C[m][n] = sum_k A[m][k] * Bt[n][k] + bias[n]
// R9 geometry (128x256, 8 waves = 4 regions 64x128 x 2 kk-roles, triple
// buffer, 0-conflict swizzle, vmcnt(6) ledger) + CROSS-BARRIER REGISTER
// PIPELINING: fragments for tile tau are read during tile tau-1, so tile
// tau's MFMAs depend only on landed registers; the tile's own ds_reads
// stream on the LDS pipe in parallel with the MFMA pipe.
//   Per tile: [A] read bh1(tau)=nj4..7 + stage tau+2 (6 gloads)
//             [B] lgkmcnt(4) (bh1 may float) -> 16 MFMA af x bh0
//             [C] lgkmcnt(0) -> [D] 16 MFMA af x bh1 (issued pre-barrier;
//                 MFMA pipe drains THROUGH the barrier)
//             [E] vmcnt(6) (drains [A] of tau-1 -> publishes buf tau+1);
//                 s_barrier
//             [F] read af(tau+1), bh0(tau+1) from buf (tau+1)%3
// Hazards: RAW buf tau+1 via [E]; WAR stage target (tau+2)%3 via [C]'s
// lgkm(0) preceding [E]'s barrier (its last readers were tau-1's [F]/[A]);
// rule-18 sched_barrier(0) after every asm wait; rule-20 manual x2 unroll
// with named register sets.
// ---------------------------------------------------------------------------
__global__ __launch_bounds__(512, 2) void gemm_bf16(
    const unsigned short* __restrict__ A,
    const unsigned short* __restrict__ Bt,
    const float* __restrict__ bias,
    float* __restrict__ C) {
    __shared__ __align__(16) char smem[147456];
    // A bufs: smem + buf*16384           (3 x 16 KiB)
    // B bufs: smem + 49152 + buf*32768   (3 x 32 KiB)
    // epilogue partials: smem + region*32768 (4 x 32 KiB, after K-loop)

    const int t      = threadIdx.x;
    const int lane   = t & 63;
    const int wave   = t >> 6;
    const int region = wave >> 1;    // 0..3 : 64x128 output region
    const int kkr    = wave & 1;     // 0/1  : K-half role
    const int rm     = region >> 1;  // 0..1 row block (x64)
    const int rn     = region & 1;   // 0..1 col block (x128)
    const int lrow   = lane & 15;
    const int lhi    = lane >> 4;

    // T1: XCD-aware swizzle (256 WGs, %8==0 -> bijective)
    const int wg  = blockIdx.x;
    const int swz = (wg & 7) * 32 + (wg >> 3);
    const int m0  = (swz >> 4) * BM;
    const int n0  = (swz & 15) * BN;

    // staging: linear LDS dest + inverse-swizzled global source
    auto stageA = [&](int buf, int tile, int c) {
        int row = c >> 3, p = c & 7;
        int l   = p ^ (row & 7);
        gload_lds16(A + (size_t)(m0 + row) * K_DIM + tile * BK + l * 8,
                    smem + buf * 16384 + c * 16);
    };
    auto stageB = [&](int buf, int tile, int c) {
        int row = c >> 3, p = c & 7;
        int l   = p ^ (row & 7);
        gload_lds16(Bt + (size_t)(n0 + row) * K_DIM + tile * BK + l * 8,
                    smem + 49152 + buf * 32768 + c * 16);
    };

    f32x4 acc[4][8];  // [mi][nj], this wave's kk-half partial
#pragma unroll
    for (int i = 0; i < 4; ++i)
#pragma unroll
        for (int j = 0; j < 8; ++j) acc[i][j] = (f32x4)0.0f;

    const int NT = K_DIM / BK;  // 64

    // fragment offsets (row&7 == lrow&7; proven 0-conflict pattern)
    const int rowOffA = (rm * 64 + lrow) * 128;          // + mi*2048, mi 0..3
    const int rowOffB = (rn * 128 + lrow) * 128;         // + nj*2048, nj 0..7
    const int sK = ((kkr * 4 + lhi) ^ (lrow & 7)) * 16;  // this wave's kk slot

    // prologue: tiles 0 and 1 fully staged (12 chunks/thread in flight)
    stageA(0, 0, t); stageA(0, 0, t + 512);
    stageB(0, 0, t); stageB(0, 0, t + 512);
    stageB(0, 0, t + 1024); stageB(0, 0, t + 1536);
    stageA(1, 1, t); stageA(1, 1, t + 512);
    stageB(1, 1, t); stageB(1, 1, t + 512);
    stageB(1, 1, t + 1024); stageB(1, 1, t + 1536);

    // publish tile 0 (drains its 6 chunks; tile 1's 6 stay in flight)
    asm volatile("s_waitcnt vmcnt(6)" ::: "memory");
    __builtin_amdgcn_s_barrier();
    __builtin_amdgcn_sched_barrier(0);

    // [F] for tile 0: af + bh0 into register set A
    bf16x8 afA[4], bhA[4], afB[4], bhB[4];
#pragma unroll
    for (int mi = 0; mi < 4; ++mi)
        afA[mi] = *(const bf16x8*)(smem + 0 * 16384 + rowOffA + mi * 2048 + sK);
#pragma unroll
    for (int nj = 0; nj < 4; ++nj)
        bhA[nj] = *(const bf16x8*)(smem + 49152 + 0 * 32768 + rowOffB + nj * 2048 + sK);

    // TILE body: consume (afU,bhU) for tile tau; load (afN,bhN) for tau+1
    auto TILE = [&](int tau, bf16x8 (&afU)[4], bf16x8 (&bhU)[4],
                    bf16x8 (&afN)[4], bf16x8 (&bhN)[4]) {
        const int bufC = tau % 3;
        const int bufS = (tau + 2) % 3;
        const int bufN = (tau + 1) % 3;
        const int tile2 = (tau + 2 < NT) ? tau + 2 : NT - 1;
        const char* bB = smem + 49152 + bufC * 32768;
        const char* nA = smem + bufN * 16384;
        const char* nB = smem + 49152 + bufN * 32768;

        // [A] read bh1 (nj 4..7) + stage tile tau+2
        bf16x8 bh1[4];
#pragma unroll
        for (int nj = 0; nj < 4; ++nj)
            bh1[nj] = *(const bf16x8*)(bB + rowOffB + (nj + 4) * 2048 + sK);
        stageA(bufS, tile2, t);
        stageA(bufS, tile2, t + 512);
        stageB(bufS, tile2, t);
        stageB(bufS, tile2, t + 512);
        stageB(bufS, tile2, t + 1024);
        stageB(bufS, tile2, t + 1536);

        // [B] wait prev-tile [F] reads (allow bh1's 4 to float); MFMA H0
        asm volatile("s_waitcnt lgkmcnt(4)" ::: "memory");
        __builtin_amdgcn_sched_barrier(0);
        __builtin_amdgcn_s_setprio(1);
#pragma unroll
        for (int mi = 0; mi < 4; ++mi)
#pragma unroll
            for (int nj = 0; nj < 4; ++nj)
                acc[mi][nj] = __builtin_amdgcn_mfma_f32_16x16x32_bf16(
                    afU[mi], bhU[nj], acc[mi][nj], 0, 0, 0);
        __builtin_amdgcn_s_setprio(0);

        // [C] all reads landed (also WAR guarantee for this buffer family)
        asm volatile("s_waitcnt lgkmcnt(0)" ::: "memory");
        __builtin_amdgcn_sched_barrier(0);

        // [D] MFMA H1 — issued pre-barrier; pipe drains through [E]
        __builtin_amdgcn_s_setprio(1);
#pragma unroll
        for (int mi = 0; mi < 4; ++mi)
#pragma unroll
            for (int nj = 0; nj < 4; ++nj)
                acc[mi][nj + 4] = __builtin_amdgcn_mfma_f32_16x16x32_bf16(
                    afU[mi], bh1[nj], acc[mi][nj + 4], 0, 0, 0);
        __builtin_amdgcn_s_setprio(0);
        __builtin_amdgcn_sched_barrier(0);

        // [E] publish buf tau+1 (drains [A]-batch of tau-1); block-wide
        asm volatile("s_waitcnt vmcnt(6)" ::: "memory");
        __builtin_amdgcn_s_barrier();
        __builtin_amdgcn_sched_barrier(0);

        // [F] read af + bh0 of tile tau+1 (overlaps [D]'s pipe drain)
#pragma unroll
        for (int mi = 0; mi < 4; ++mi)
            afN[mi] = *(const bf16x8*)(nA + rowOffA + mi * 2048 + sK);
#pragma unroll
        for (int nj = 0; nj < 4; ++nj)
            bhN[nj] = *(const bf16x8*)(nB + rowOffB + nj * 2048 + sK);
    };

    for (int tau = 0; tau < NT; tau += 2) {
        TILE(tau,     afA, bhA, afB, bhB);
        TILE(tau + 1, afB, bhB, afA, bhA);
    }

    // ---- epilogue: combine kk pair via (dead) LDS, write C + bias ----
    __syncthreads();
    if (kkr == 1) {
#pragma unroll
        for (int mi = 0; mi < 4; ++mi)
#pragma unroll
            for (int nj = 0; nj < 8; ++nj)
                *(f32x4*)(smem + region * 32768 +
                          ((mi * 8 + nj) * 64 + lane) * 16) = acc[mi][nj];
    }
    __syncthreads();
    if (kkr == 0) {
        // C/D layout: col=lane&15, row=(lane>>4)*4+reg
#pragma unroll
        for (int nj = 0; nj < 8; ++nj) {
            int col  = n0 + rn * 128 + nj * 16 + lrow;
            float bv = bias[col];
#pragma unroll
            for (int mi = 0; mi < 4; ++mi) {
                f32x4 p = *(const f32x4*)(smem + region * 32768 +
                                          ((mi * 8 + nj) * 64 + lane) * 16);
                int rbase = m0 + rm * 64 + mi * 16 + lhi * 4;
#pragma unroll
                for (int r = 0; r < 4; ++r) {
                    C[(size_t)(rbase + r) * N_DIM + col] =
                        acc[mi][nj][r] + p[r] + bv;
                }
            }
        }
    }
}

// ---------------------------------------------------------------------------
extern "C" void kernel_launch(void* const* d_in, const int* in_sizes, int n_in,
                              void* d_out, int out_size, void* d_ws, size_t ws_size,
                              hipStream_t stream) {
    const float* x    = (const float*)d_in[0];
    const float* w    = (const float*)d_in[1];
    const float* bias = (const float*)d_in[2];
    float* out        = (float*)d_out;

    unsigned short* xb = (unsigned short*)d_ws;
    unsigned short* wt = (unsigned short*)((char*)d_ws +
                          (size_t)M_DIM * K_DIM * sizeof(unsigned short));

    convert_x_kernel<<<2048, 256, 0, stream>>>(x, xb, M_DIM * K_DIM / 8);

    dim3 tgrid(N_DIM / 64, K_DIM / 64);
    transpose_convert_w<<<tgrid, 256, 0, stream>>>(w, wt);

    dim3 ggrid((M_DIM / BM) * (N_DIM / BN));
    gemm_bf16<<<ggrid, 512, 0, stream>>>(xb, wt, bias, out);
}